// Round 2
// baseline (1909.210 us; speedup 1.0000x reference)
//
#include <hip/hip_runtime.h>
#include <math.h>

#define HID 128

// DPP wave64 reduction stage: v += dpp_shifted(v)
template<int CTRL, int RMASK>
__device__ __forceinline__ float dpp_add_stage(float v) {
  int s = __builtin_amdgcn_update_dpp(0, __float_as_int(v), CTRL, RMASK, 0xf, true);
  return v + __int_as_float(s);
}

// After this, lane 63 of the wave holds the 64-lane total.
__device__ __forceinline__ float wave_red_sum_l63(float v) {
  v = dpp_add_stage<0x111, 0xf>(v);  // row_shr:1
  v = dpp_add_stage<0x112, 0xf>(v);  // row_shr:2
  v = dpp_add_stage<0x114, 0xf>(v);  // row_shr:4
  v = dpp_add_stage<0x118, 0xf>(v);  // row_shr:8  -> lane15 of each 16-row
  v = dpp_add_stage<0x142, 0xa>(v);  // row_bcast:15 -> rows 1,3
  v = dpp_add_stage<0x143, 0xc>(v);  // row_bcast:31 -> rows 2,3; lane63 = total
  return v;
}

#define REPEAT32(F) F(0)F(1)F(2)F(3)F(4)F(5)F(6)F(7)F(8)F(9)F(10)F(11)F(12)F(13)F(14)F(15)F(16)F(17)F(18)F(19)F(20)F(21)F(22)F(23)F(24)F(25)F(26)F(27)F(28)F(29)F(30)F(31)

// 128 threads (2 waves) per block, one batch element per block.
// Lane tid owns hidden row tid; its 128 weights live in 32 NAMED float4
// registers (no alloca -> guaranteed VGPR residency, ~128 regs).
__global__ __launch_bounds__(128, 2) void snn_fused_kernel(
    const float* __restrict__ x, const float* __restrict__ Win,
    const float* __restrict__ b_in, const float* __restrict__ ln_g,
    const float* __restrict__ ln_b, const float* __restrict__ Wout,
    const float* __restrict__ b_out, float* __restrict__ out, int T) {
  __shared__ float4 xrow4[512];   // x[b, :, :]  (T<=512)
  __shared__ float4 enc4[32];     // 128 encoding values for current step
  __shared__ float  red[4];       // cross-wave LN partials {s1_w0,s2_w0,s1_w1,s2_w1}

  const int b = blockIdx.x;
  const int tid = threadIdx.x;    // 0..127
  const int wid = tid >> 6;       // wave id 0/1

  // Stage x[b] into LDS (coalesced float4).
  const float4* xg = (const float4*)(x + (size_t)b * (size_t)T * 4);
  for (int i = tid; i < T; i += 128) xrow4[i] = xg[i];

  // Weight row tid -> 32 named float4 registers.
  const float4* wr = (const float4*)(Win + tid * HID);
#define DECLW(i) float4 w##i = wr[i];
  REPEAT32(DECLW)
#undef DECLW

  // Per-lane constants for row tid.
  const float bin = b_in[tid];
  const float g   = ln_g[tid];
  const float bLN = ln_b[tid];
  const float wo0 = Wout[tid];
  const float wo1 = Wout[HID + tid];

  // Gaussian threshold-encoding constants: row tid = channel (tid>>5), thr (tid&31).
  const int   ch  = tid >> 5;
  const float th  = (float)(-3.0 + (double)(tid & 31) * (6.0 / 31.0));
  const float coef = (float)(-0.5 * 1024.0 / 25.0);  // -0.5/sigma^2

  float mem = 0.f;
  float ro0 = 0.f, ro1 = 0.f;     // per-lane readout partials

  __syncthreads();

  for (int t = 0; t < T; ++t) {
    // --- encoding: each lane computes its single enc value ---
    float4 xt = xrow4[t];                          // uniform LDS read
    float xc = (ch & 2) ? ((ch & 1) ? xt.w : xt.z)
                        : ((ch & 1) ? xt.y : xt.x);
    float d = xc - th;
    float e = __expf(coef * d * d);
    ((float*)enc4)[tid] = e;
    __syncthreads();                               // B1: enc visible

    // --- h = dot(W_row, enc): 32 uniform b128 broadcasts, 128 FMAs, 4 chains ---
    float h0 = 0.f, h1 = 0.f, h2 = 0.f, h3 = 0.f;
#define DOFMA(i) { float4 ev = enc4[i]; float4 wv = w##i; \
    h0 = fmaf(wv.x, ev.x, h0); h1 = fmaf(wv.y, ev.y, h1); \
    h2 = fmaf(wv.z, ev.z, h2); h3 = fmaf(wv.w, ev.w, h3); }
    REPEAT32(DOFMA)
#undef DOFMA
    float h = ((h0 + h1) + (h2 + h3)) + bin;

    // --- LayerNorm over 128 lanes (2 waves): DPP partial + LDS combine ---
    float p1 = wave_red_sum_l63(h);
    float p2 = wave_red_sum_l63(h * h);
    if ((tid & 63) == 63) { red[2 * wid] = p1; red[2 * wid + 1] = p2; }
    __syncthreads();                               // B2: red visible
    float4 r4 = *(const float4*)red;               // uniform broadcast read
    float s1 = r4.x + r4.z;
    float s2 = r4.y + r4.w;
    float mu   = s1 * (1.0f / 128.0f);
    float var  = s2 * (1.0f / 128.0f) - mu * mu;
    float rstd = 1.0f / sqrtf(var + 1e-5f);
    float gs = g * rstd;
    float c  = fmaf(h - mu, gs, bLN);

    // --- membrane / spike / soft reset / readout partials ---
    mem = fmaf(mem, 0.9f, c * 0.1f);
    float sp = (mem > 0.5f) ? 1.0f : 0.0f;
    mem = fmaf(sp, -0.5f, mem);
    ro0 = fmaf(sp, wo0, ro0);
    ro1 = fmaf(sp, wo1, ro1);
    // WAR safety: enc(t+1) writes happen after B2; red(t+1) writes happen
    // after next B1; all reads of this step precede those barriers.
  }

  // --- final readout reduction across 128 lanes ---
  float r0 = wave_red_sum_l63(ro0);
  float r1 = wave_red_sum_l63(ro1);
  __syncthreads();                                 // red[] reuse
  if ((tid & 63) == 63) { red[2 * wid] = r0; red[2 * wid + 1] = r1; }
  __syncthreads();
  if (tid == 0) {
    out[2 * b]     = (red[0] + red[2]) + (float)T * b_out[0];
    out[2 * b + 1] = (red[1] + red[3]) + (float)T * b_out[1];
  }
}

extern "C" void kernel_launch(void* const* d_in, const int* in_sizes, int n_in,
                              void* d_out, int out_size, void* d_ws, size_t ws_size,
                              hipStream_t stream) {
  const float* x    = (const float*)d_in[0];
  const float* Win  = (const float*)d_in[1];
  const float* bin  = (const float*)d_in[2];
  const float* lng  = (const float*)d_in[3];
  const float* lnb  = (const float*)d_in[4];
  const float* Wout = (const float*)d_in[5];
  const float* bout = (const float*)d_in[6];
  float* out = (float*)d_out;

  int B = out_size / 2;                 // 2048
  int T = in_sizes[0] / (B * 4);        // 512

  snn_fused_kernel<<<dim3(B), dim3(128), 0, stream>>>(
      x, Win, bin, lng, lnb, Wout, bout, out, T);
}

// Round 3
// 1182.455 us; speedup vs baseline: 1.6146x; 1.6146x over previous
//
#include <hip/hip_runtime.h>
#include <math.h>

#define HID 128

// DPP wave64 reduction stage: v += dpp_shifted(v)
template<int CTRL, int RMASK>
__device__ __forceinline__ float dpp_add_stage(float v) {
  int s = __builtin_amdgcn_update_dpp(0, __float_as_int(v), CTRL, RMASK, 0xf, true);
  return v + __int_as_float(s);
}

// After this, lane 63 of the wave holds the 64-lane total.
__device__ __forceinline__ float wave_red_sum_l63(float v) {
  v = dpp_add_stage<0x111, 0xf>(v);  // row_shr:1
  v = dpp_add_stage<0x112, 0xf>(v);  // row_shr:2
  v = dpp_add_stage<0x114, 0xf>(v);  // row_shr:4
  v = dpp_add_stage<0x118, 0xf>(v);  // row_shr:8  -> lane15 of each 16-row
  v = dpp_add_stage<0x142, 0xa>(v);  // row_bcast:15 -> rows 1,3
  v = dpp_add_stage<0x143, 0xc>(v);  // row_bcast:31 -> rows 2,3; lane63 = total
  return v;
}

#define REPEAT32(F) F(0)F(1)F(2)F(3)F(4)F(5)F(6)F(7)F(8)F(9)F(10)F(11)F(12)F(13)F(14)F(15)F(16)F(17)F(18)F(19)F(20)F(21)F(22)F(23)F(24)F(25)F(26)F(27)F(28)F(29)F(30)F(31)

// 128 threads (2 waves) per block, one batch element per block.
// Lane tid owns hidden row tid; its 128 weights live in 32 named float4s,
// pinned to VGPRs via asm (non-rematerializable) under a >=256-reg cap.
__global__ __launch_bounds__(128, 1) void snn_fused_kernel(
    const float* __restrict__ x, const float* __restrict__ Win,
    const float* __restrict__ b_in, const float* __restrict__ ln_g,
    const float* __restrict__ ln_b, const float* __restrict__ Wout,
    const float* __restrict__ b_out, float* __restrict__ out, int T) {
  __shared__ float4 xrow4[512];      // x[b, :, :]  (T<=512)
  __shared__ float4 enc4[2][32];     // double-buffered 128 encodings
  __shared__ float  red[2][4];       // double-buffered LN partials per wave

  const int b = blockIdx.x;
  const int tid = threadIdx.x;       // 0..127
  const int wid = tid >> 6;          // wave id 0/1

  // Stage x[b] into LDS (coalesced float4).
  const float4* xg = (const float4*)(x + (size_t)b * (size_t)T * 4);
  for (int i = tid; i < T; i += 128) xrow4[i] = xg[i];

  // Weight row tid -> 32 named float4 registers, pinned against remat.
  const float4* wr = (const float4*)(Win + tid * HID);
#define DECLW(i) float4 w##i = wr[i]; \
  asm("" : "+v"(w##i.x), "+v"(w##i.y), "+v"(w##i.z), "+v"(w##i.w));
  REPEAT32(DECLW)
#undef DECLW

  // Per-lane constants for row tid.
  const float bin = b_in[tid];
  const float g   = ln_g[tid];
  const float bLN = ln_b[tid];
  const float wo0 = Wout[tid];
  const float wo1 = Wout[HID + tid];

  // Gaussian threshold-encoding constants: lane tid = channel (tid>>5), thr (tid&31).
  const int   ch   = tid >> 5;
  const float th   = (float)(-3.0 + (double)(tid & 31) * (6.0 / 31.0));
  const float coef = (float)(-0.5 * 1024.0 / 25.0);  // -0.5/sigma^2

  float mem = 0.f;
  float ro0 = 0.f, ro1 = 0.f;        // per-lane readout partials

  __syncthreads();                   // xrow4 ready

  // Prologue: enc(0) into buffer 0.
  {
    float4 xt = xrow4[0];
    float xc = (ch & 2) ? ((ch & 1) ? xt.w : xt.z)
                        : ((ch & 1) ? xt.y : xt.x);
    float d = xc - th;
    ((float*)enc4[0])[tid] = __expf(coef * d * d);
  }
  __syncthreads();

  for (int t = 0; t < T; ++t) {
    const int p = t & 1;

    // --- h = dot(W_row, enc(t)): 32 uniform b128 broadcasts, 128 FMAs ---
    float h0 = 0.f, h1 = 0.f, h2 = 0.f, h3 = 0.f;
#define DOFMA(i) { float4 ev = enc4[p][i]; \
    h0 = fmaf(w##i.x, ev.x, h0); h1 = fmaf(w##i.y, ev.y, h1); \
    h2 = fmaf(w##i.z, ev.z, h2); h3 = fmaf(w##i.w, ev.w, h3); }
    REPEAT32(DOFMA)
#undef DOFMA
    float h = ((h0 + h1) + (h2 + h3)) + bin;

    // --- LN partials (DPP) -> red[p] ---
    float p1 = wave_red_sum_l63(h);
    float p2 = wave_red_sum_l63(h * h);
    if ((tid & 63) == 63) { red[p][2 * wid] = p1; red[p][2 * wid + 1] = p2; }

    // --- pipeline: enc(t+1) into the other buffer (clamped on last iter) ---
    {
      int tn = (t + 1 < T) ? (t + 1) : t;
      float4 xt = xrow4[tn];
      float xc = (ch & 2) ? ((ch & 1) ? xt.w : xt.z)
                          : ((ch & 1) ? xt.y : xt.x);
      float d = xc - th;
      ((float*)enc4[p ^ 1])[tid] = __expf(coef * d * d);
    }

    __syncthreads();  // covers: red[p] RAW, enc(t+1) RAW, enc-buffer WAR

    // --- LN finish ---
    float4 r4 = *(const float4*)red[p];          // uniform broadcast read
    float s1 = r4.x + r4.z;
    float s2 = r4.y + r4.w;
    float mu   = s1 * (1.0f / 128.0f);
    float var  = s2 * (1.0f / 128.0f) - mu * mu;
    float rstd = 1.0f / sqrtf(var + 1e-5f);
    float c  = fmaf(h - mu, g * rstd, bLN);

    // --- membrane / spike / soft reset / readout partials ---
    mem = fmaf(mem, 0.9f, c * 0.1f);
    float sp = (mem > 0.5f) ? 1.0f : 0.0f;
    mem = fmaf(sp, -0.5f, mem);
    ro0 = fmaf(sp, wo0, ro0);
    ro1 = fmaf(sp, wo1, ro1);
  }

  // --- final readout reduction across 128 lanes ---
  float r0 = wave_red_sum_l63(ro0);
  float r1 = wave_red_sum_l63(ro1);
  __syncthreads();                               // red[] reuse
  if ((tid & 63) == 63) { red[0][2 * wid] = r0; red[0][2 * wid + 1] = r1; }
  __syncthreads();
  if (tid == 0) {
    out[2 * b]     = (red[0][0] + red[0][2]) + (float)T * b_out[0];
    out[2 * b + 1] = (red[0][1] + red[0][3]) + (float)T * b_out[1];
  }
}

extern "C" void kernel_launch(void* const* d_in, const int* in_sizes, int n_in,
                              void* d_out, int out_size, void* d_ws, size_t ws_size,
                              hipStream_t stream) {
  const float* x    = (const float*)d_in[0];
  const float* Win  = (const float*)d_in[1];
  const float* bin  = (const float*)d_in[2];
  const float* lng  = (const float*)d_in[3];
  const float* lnb  = (const float*)d_in[4];
  const float* Wout = (const float*)d_in[5];
  const float* bout = (const float*)d_in[6];
  float* out = (float*)d_out;

  int B = out_size / 2;                 // 2048
  int T = in_sizes[0] / (B * 4);        // 512

  snn_fused_kernel<<<dim3(B), dim3(128), 0, stream>>>(
      x, Win, bin, lng, lnb, Wout, bout, out, T);
}

// Round 4
// 1115.878 us; speedup vs baseline: 1.7109x; 1.0597x over previous
//
#include <hip/hip_runtime.h>
#include <math.h>

#define HID 128

// ---------- DPP helpers ----------
template<int CTRL, int RMASK>
__device__ __forceinline__ float dpp_add_stage(float v) {
  int s = __builtin_amdgcn_update_dpp(0, __float_as_int(v), CTRL, RMASK, 0xf, true);
  return v + __int_as_float(s);
}
// Full 64-lane sum broadcast to all lanes (verified in rounds 1-3).
__device__ __forceinline__ float wave_red_sum(float v) {
  v = dpp_add_stage<0x111, 0xf>(v);  // row_shr:1
  v = dpp_add_stage<0x112, 0xf>(v);  // row_shr:2
  v = dpp_add_stage<0x114, 0xf>(v);  // row_shr:4
  v = dpp_add_stage<0x118, 0xf>(v);  // row_shr:8
  v = dpp_add_stage<0x142, 0xa>(v);  // row_bcast:15
  v = dpp_add_stage<0x143, 0xc>(v);  // row_bcast:31 -> lane63 total
  return __int_as_float(__builtin_amdgcn_readlane(__float_as_int(v), 63));
}
// row_ror:1 (DPP ctrl 0x121): rotate within each 16-lane row.
__device__ __forceinline__ float ror1(float v) {
  return __int_as_float(__builtin_amdgcn_update_dpp(0, __float_as_int(v), 0x121, 0xf, 0xf, true));
}
// ds_bpermute: "pull" — this lane receives src from lane (addr>>2). Unambiguous.
__device__ __forceinline__ float bperm(int srclane, float v) {
  return __int_as_float(__builtin_amdgcn_ds_bpermute(srclane << 2, __float_as_int(v)));
}

#define REP8Q(F, j) F(0,0,j) F(1,1,j) F(2,2,j) F(3,3,j) F(4,0,j) F(5,1,j) F(6,2,j) F(7,3,j)
#define REP16J(F) F(0) F(1) F(2) F(3) F(4) F(5) F(6) F(7) F(8) F(9) F(10) F(11) F(12) F(13) F(14) F(15)

// One wave (64 lanes) per batch element. Lane owns hidden rows lane, lane+64.
// 256 weight f32s in named VGPRs; enc delivered by register rotation (no LDS
// broadcast). waves_per_eu(1,1): RA budget 512 VGPRs, no occupancy pressure.
__global__ __attribute__((amdgpu_waves_per_eu(1, 1))) __launch_bounds__(64)
void snn_fused_kernel(
    const float* __restrict__ x, const float* __restrict__ Win,
    const float* __restrict__ b_in, const float* __restrict__ ln_g,
    const float* __restrict__ ln_b, const float* __restrict__ Wout,
    const float* __restrict__ b_out, float* __restrict__ out, int T) {
  __shared__ float4 xrow4[512];                 // x[b, :, :], T<=512

  const int b    = blockIdx.x;
  const int lane = threadIdx.x;                  // 0..63
  const int g    = lane >> 4;                    // 16-lane row group 0..3
  const int i    = lane & 15;                    // index within row
  const int row0 = lane, row1 = lane + 64;

  // Stage x[b] into LDS (single wave: in-order DS pipe, no barrier needed).
  const float4* xg = (const float4*)(x + (size_t)b * (size_t)T * 4);
  for (int k = lane; k < T; k += 64) xrow4[k] = xg[k];

  // --- Runtime probe of row_ror:1 direction; fold sign into weight indices ---
  // After 1 rotation, lane (g,0) holds the lane-id of row-lane ((0 - s) & 15):
  // 15 if s=+1 (lane i <- lane i-1), 1 if s=-1.
  int s_dir;
  {
    int probe = __builtin_amdgcn_update_dpp(0, lane, 0x121, 0xf, 0xf, true);
    s_dir = ((__builtin_amdgcn_readfirstlane(probe) & 15) == 15) ? 1 : -1;
  }

  // --- Weight preload: w{r}_{q}_{j} = Win[row_r, k(q,j)] where
  // k(q,j) = 64*(q>>2) + 16*((g+q)&3) + ((i - s*j)&15)  (rotation schedule) ---
#define LOADW(q, c, j) \
  float w0_##q##_##j, w1_##q##_##j; \
  { int kk = (64 * ((q) >> 2) + 16 * ((g + (q)) & 3)) + ((i - s_dir * (j)) & 15); \
    w0_##q##_##j = Win[(size_t)row0 * HID + kk]; \
    w1_##q##_##j = Win[(size_t)row1 * HID + kk]; \
    asm("" : "+v"(w0_##q##_##j), "+v"(w1_##q##_##j)); }
#define LOADJ(j) REP8Q(LOADW, j)
  REP16J(LOADJ)
#undef LOADJ

  // Per-lane constants.
  const float binA = b_in[row0], binB = b_in[row1];
  const float gA = ln_g[row0], gB = ln_g[row1];
  const float bA = ln_b[row0], bB = ln_b[row1];
  const float woA0 = Wout[row0], woB0 = Wout[row1];
  const float woA1 = Wout[HID + row0], woB1 = Wout[HID + row1];

  // Gaussian encoding constants (enc index lane -> ch lane>>5, thr lane&31;
  // enc index lane+64 -> ch 2+(lane>>5), same thr).
  const float th   = (float)(-3.0 + (double)(lane & 31) * (6.0 / 31.0));
  const float coef = (float)(-0.5 * 1024.0 / 25.0);

  float mem0 = 0.f, mem1 = 0.f;
  float ro0 = 0.f, ro1 = 0.f;

  for (int t = 0; t < T; ++t) {
    // --- encoding: lane computes enc[lane] (e0) and enc[lane+64] (e1) ---
    float4 xt = xrow4[t];                        // uniform LDS read
    float xc0 = (lane < 32) ? xt.x : xt.y;
    float xc1 = (lane < 32) ? xt.z : xt.w;
    float d0 = xc0 - th, d1 = xc1 - th;
    float e0 = __expf(coef * d0 * d0);
    float e1 = __expf(coef * d1 * d1);

    // --- seed 8 rotation registers via bpermute (no LDS array traffic) ---
    // r_q at lane (g,i) = enc[64*(q>>2) + 16*((g+q)&3) + i]
    float r0, r1, r2, r3, r4, r5, r6, r7;
#define SETR(q, c, j) r##q = bperm(16 * ((g + (q)) & 3) + i, ((q) < 4) ? e0 : e1);
    REP8Q(SETR, 0)
#undef SETR

    // --- systolic dot product: 16 consume-steps, 15 rotations ---
    float h0_0 = 0.f, h0_1 = 0.f, h0_2 = 0.f, h0_3 = 0.f;
    float h1_0 = 0.f, h1_1 = 0.f, h1_2 = 0.f, h1_3 = 0.f;
#define FMA1(q, c, j) \
    h0_##c = fmaf(r##q, w0_##q##_##j, h0_##c); \
    h1_##c = fmaf(r##q, w1_##q##_##j, h1_##c);
#define ROTALL r0=ror1(r0); r1=ror1(r1); r2=ror1(r2); r3=ror1(r3); \
               r4=ror1(r4); r5=ror1(r5); r6=ror1(r6); r7=ror1(r7);
#define STEPJ(j) REP8Q(FMA1, j) ROTALL
    STEPJ(0) STEPJ(1) STEPJ(2) STEPJ(3) STEPJ(4) STEPJ(5) STEPJ(6) STEPJ(7)
    STEPJ(8) STEPJ(9) STEPJ(10) STEPJ(11) STEPJ(12) STEPJ(13) STEPJ(14)
    REP8Q(FMA1, 15)                              // last step: no rotation
#undef STEPJ
#undef ROTALL
#undef FMA1

    float h0 = ((h0_0 + h0_1) + (h0_2 + h0_3)) + binA;
    float h1 = ((h1_0 + h1_1) + (h1_2 + h1_3)) + binB;

    // --- LayerNorm over 128 rows (2 per lane), DPP-only ---
    float s1 = wave_red_sum(h0 + h1);
    float s2 = wave_red_sum(fmaf(h0, h0, h1 * h1));
    float mu   = s1 * (1.0f / 128.0f);
    float var  = s2 * (1.0f / 128.0f) - mu * mu;
    float rstd = 1.0f / sqrtf(var + 1e-5f);
    float c0 = fmaf((h0 - mu) * rstd, gA, bA);
    float c1 = fmaf((h1 - mu) * rstd, gB, bB);

    // --- membrane / spike / soft reset / readout partials ---
    mem0 = fmaf(mem0, 0.9f, c0 * 0.1f);
    mem1 = fmaf(mem1, 0.9f, c1 * 0.1f);
    float sp0 = (mem0 > 0.5f) ? 1.0f : 0.0f;
    float sp1 = (mem1 > 0.5f) ? 1.0f : 0.0f;
    mem0 = fmaf(sp0, -0.5f, mem0);
    mem1 = fmaf(sp1, -0.5f, mem1);
    ro0 = fmaf(sp0, woA0, ro0); ro0 = fmaf(sp1, woB0, ro0);
    ro1 = fmaf(sp0, woA1, ro1); ro1 = fmaf(sp1, woB1, ro1);
  }

  float R0 = wave_red_sum(ro0);
  float R1 = wave_red_sum(ro1);
  if (lane == 0) {
    out[2 * b]     = R0 + (float)T * b_out[0];
    out[2 * b + 1] = R1 + (float)T * b_out[1];
  }
}

extern "C" void kernel_launch(void* const* d_in, const int* in_sizes, int n_in,
                              void* d_out, int out_size, void* d_ws, size_t ws_size,
                              hipStream_t stream) {
  const float* x    = (const float*)d_in[0];
  const float* Win  = (const float*)d_in[1];
  const float* bin  = (const float*)d_in[2];
  const float* lng  = (const float*)d_in[3];
  const float* lnb  = (const float*)d_in[4];
  const float* Wout = (const float*)d_in[5];
  const float* bout = (const float*)d_in[6];
  float* out = (float*)d_out;

  int B = out_size / 2;                 // 2048
  int T = in_sizes[0] / (B * 4);        // 512

  snn_fused_kernel<<<dim3(B), dim3(64), 0, stream>>>(
      x, Win, bin, lng, lnb, Wout, bout, out, T);
}

// Round 6
// 187.105 us; speedup vs baseline: 10.2039x; 5.9639x over previous
//
#include <hip/hip_runtime.h>
#include <math.h>

#define HID 128
#define TT 32

typedef __attribute__((ext_vector_type(8))) short short8v;   // 8 bf16 = 4 VGPRs
typedef __attribute__((ext_vector_type(16))) float f32x16;   // MFMA 32x32 acc

// ---------- DPP wave64 sum (verified R1-R4) ----------
template<int CTRL, int RMASK>
__device__ __forceinline__ float dpp_add_stage(float v) {
  int s = __builtin_amdgcn_update_dpp(0, __float_as_int(v), CTRL, RMASK, 0xf, true);
  return v + __int_as_float(s);
}
__device__ __forceinline__ float wave_red_sum(float v) {
  v = dpp_add_stage<0x111, 0xf>(v);
  v = dpp_add_stage<0x112, 0xf>(v);
  v = dpp_add_stage<0x114, 0xf>(v);
  v = dpp_add_stage<0x118, 0xf>(v);
  v = dpp_add_stage<0x142, 0xa>(v);
  v = dpp_add_stage<0x143, 0xc>(v);
  return __int_as_float(__builtin_amdgcn_readlane(__float_as_int(v), 63));
}

#define REP8(F) F(0) F(1) F(2) F(3) F(4) F(5) F(6) F(7)

// Encode one 32-step tile of Gaussian threshold encoding into bf16 hi/lo LDS
// buffers (chunk-XOR-swizzled). 128 threads: tid2 = (t<<2) | channel.
__device__ __forceinline__ void encode_tile(
    int tid2, int tile, unsigned int* Eh, unsigned int* El,
    const float4* xrow4) {
  const int t5 = tid2 >> 2;       // 0..31  (t within tile)
  const int ch = tid2 & 3;        // channel
  const float coef = (float)(-0.5 * 1024.0 / 25.0);
  float4 xt = xrow4[tile * TT + t5];
  float xc = (ch & 2) ? ((ch & 1) ? xt.w : xt.z) : ((ch & 1) ? xt.y : xt.x);
#pragma unroll
  for (int c2 = 0; c2 < 4; ++c2) {          // 4 chunks of 8 thresholds
    unsigned int hi4[4], lo4[4];
#pragma unroll
    for (int p = 0; p < 4; ++p) {           // pairs within chunk
      int j0 = c2 * 8 + p * 2;
      float th0 = fmaf((float)j0, 6.0f / 31.0f, -3.0f);
      float th1 = fmaf((float)(j0 + 1), 6.0f / 31.0f, -3.0f);
      float d0 = xc - th0, d1 = xc - th1;
      float e0 = __expf(coef * d0 * d0);
      float e1 = __expf(coef * d1 * d1);
      unsigned u0 = __float_as_uint(e0) + 0x8000u;   // RN bf16 hi
      unsigned u1 = __float_as_uint(e1) + 0x8000u;
      hi4[p] = __builtin_amdgcn_perm(u1, u0, 0x07060302u);
      float l0 = e0 - __uint_as_float(u0 & 0xffff0000u);
      float l1 = e1 - __uint_as_float(u1 & 0xffff0000u);
      unsigned v0 = __float_as_uint(l0) + 0x8000u;
      unsigned v1 = __float_as_uint(l1) + 0x8000u;
      lo4[p] = __builtin_amdgcn_perm(v1, v0, 0x07060302u);
    }
    int chunk = ch * 4 + c2;
    int idx = t5 * 64 + ((chunk ^ (t5 & 7)) << 2);   // swizzled dword index
    *(uint4*)&Eh[idx] = make_uint4(hi4[0], hi4[1], hi4[2], hi4[3]);
    *(uint4*)&El[idx] = make_uint4(lo4[0], lo4[1], lo4[2], lo4[3]);
  }
}

// 4 waves / block, 1 batch element / block. Wave w owns output rows 32w..32w+31.
// Per tile of 32 timesteps: MFMA (bf16 hi/lo split) -> LN (frag layout) ->
// LDS transpose -> 128-thread-parallel membrane scan ‖ next-tile encoding.
__global__ __launch_bounds__(256, 2) void snn_mfma_kernel(
    const float* __restrict__ x, const float* __restrict__ Win,
    const float* __restrict__ b_in, const float* __restrict__ ln_g,
    const float* __restrict__ ln_b, const float* __restrict__ Wout,
    const float* __restrict__ b_out, float* __restrict__ out, int T) {
  __shared__ float4 xrow4[512];                 // 8 KB  x[b,:,:]
  __shared__ unsigned int Ebuf[2][2][TT * 64];  // 32 KB [buf][hi/lo] bf16x2, swizzled
  __shared__ float Hn[TT * HID];                // 16 KB (h-mu)*rstd, row^t swizzle
  __shared__ float red[256];                    // 1 KB  LN partials / epilogue

  const int tid = threadIdx.x;
  const int w   = tid >> 6;        // wave 0..3 = M-tile
  const int l   = tid & 63;
  const int hh  = l >> 5;          // lane half -> k-subchunk
  const int l31 = l & 31;          // A row / B col (=t) within tile
  const int b   = blockIdx.x;
  const int ntiles = T / TT;

  // stage x[b]
  const float4* xg = (const float4*)(x + (size_t)b * (size_t)T * 4);
  for (int i = tid; i < T; i += 256) xrow4[i] = xg[i];

  // ---- A fragments: W rows 32w+l31, k = kt*16 + hh*8 + j ; bf16 hi/lo ----
  const float* wrow = Win + (size_t)(32 * w + l31) * HID + hh * 8;
#define LDW(kt) short8v wh##kt, wl##kt; { \
    float tmp[8]; \
    *(float4*)&tmp[0] = *(const float4*)(wrow + (kt) * 16); \
    *(float4*)&tmp[4] = *(const float4*)(wrow + (kt) * 16 + 4); \
    _Pragma("unroll") \
    for (int e = 0; e < 8; ++e) { \
      unsigned u = __float_as_uint(tmp[e]) + 0x8000u; \
      wh##kt[e] = (short)(u >> 16); \
      float lof = tmp[e] - __uint_as_float(u & 0xffff0000u); \
      wl##kt[e] = (short)((__float_as_uint(lof) + 0x8000u) >> 16); \
    } }
  REP8(LDW)
#undef LDW

  // bias per C/D fragment row: row = 32w + 4*hh + (r&3) + 8*(r>>2)
  float binv[16];
#pragma unroll
  for (int r = 0; r < 16; ++r) binv[r] = b_in[32 * w + 4 * hh + (r & 3) + 8 * (r >> 2)];

  // scan-phase constants (threads 0..127 use them; masked index keeps loads uniform)
  const int srow = tid & 127;
  const float gr = ln_g[srow], br = ln_b[srow];
  const float wo0 = Wout[srow], wo1 = Wout[HID + srow];
  float mem = 0.f, ro0 = 0.f, ro1 = 0.f;

  __syncthreads();
  if (tid >= 128) encode_tile(tid - 128, 0, &Ebuf[0][0][0], &Ebuf[0][1][0], xrow4);
  __syncthreads();

  for (int tau = 0; tau < ntiles; ++tau) {
    const int cur = tau & 1;
    const unsigned int* Eh = &Ebuf[cur][0][0];
    const unsigned int* El = &Ebuf[cur][1][0];
    const int t5 = l31;            // this lane's output column (=t)
    const int sw = t5 & 7;

    // ---- B fragments from swizzled LDS: k = kt*16 + hh*8 + j, col t5 ----
#define RDB(kt) \
    short8v bh##kt = *(const short8v*)&Eh[t5 * 64 + (((2 * (kt) + hh) ^ sw) << 2)]; \
    short8v bl##kt = *(const short8v*)&El[t5 * 64 + (((2 * (kt) + hh) ^ sw) << 2)];
    REP8(RDB)
#undef RDB

    // ---- 24 MFMAs, 3 interleaved acc chains ----
    f32x16 accA, accB, accC;
#pragma unroll
    for (int r = 0; r < 16; ++r) { accA[r] = 0.f; accB[r] = 0.f; accC[r] = 0.f; }
#define MM(kt) \
    accA = __builtin_amdgcn_mfma_f32_32x32x16_bf16(wh##kt, bh##kt, accA, 0, 0, 0); \
    accB = __builtin_amdgcn_mfma_f32_32x32x16_bf16(wh##kt, bl##kt, accB, 0, 0, 0); \
    accC = __builtin_amdgcn_mfma_f32_32x32x16_bf16(wl##kt, bh##kt, accC, 0, 0, 0);
    REP8(MM)
#undef MM

    // ---- h + per-(wave,col) LN partials ----
    float s1 = 0.f, s2 = 0.f, hv[16];
#pragma unroll
    for (int r = 0; r < 16; ++r) {
      float hrv = accA[r] + (accB[r] + accC[r]) + binv[r];
      hv[r] = hrv;
      s1 += hrv;
      s2 = fmaf(hrv, hrv, s2);
    }
    s1 += __shfl_xor(s1, 32);      // combine lane halves (rows +4*hh)
    s2 += __shfl_xor(s2, 32);
    if (l < 32) *(float2*)&red[w * 64 + 2 * l31] = make_float2(s1, s2);
    __syncthreads();               // B1: partials visible

    float2 q0 = *(const float2*)&red[0 + 2 * l31];
    float2 q1 = *(const float2*)&red[64 + 2 * l31];
    float2 q2 = *(const float2*)&red[128 + 2 * l31];
    float2 q3 = *(const float2*)&red[192 + 2 * l31];
    float S1 = (q0.x + q1.x) + (q2.x + q3.x);
    float S2 = (q0.y + q1.y) + (q2.y + q3.y);
    float mu = S1 * (1.0f / 128.0f);
    float var = S2 * (1.0f / 128.0f) - mu * mu;
    float rstd = 1.0f / sqrtf(var + 1e-5f);
    float sh = -mu * rstd;

    // ---- write (h-mu)*rstd to Hn, row^t swizzle (conflict-free both ways) ----
    const int rowbase = 32 * w + 4 * hh;
#pragma unroll
    for (int r = 0; r < 16; ++r) {
      int row = rowbase + (r & 3) + 8 * (r >> 2);
      Hn[t5 * 128 + (row ^ t5)] = fmaf(hv[r], rstd, sh);
    }
    __syncthreads();               // B2: Hn ready

    if (tid < 128) {
      // ---- membrane scan: thread owns one row, loops 32 steps ----
#pragma unroll 4
      for (int tt = 0; tt < TT; ++tt) {
        float hn = Hn[tt * 128 + (tid ^ tt)];
        float c = fmaf(hn, gr, br);
        mem = fmaf(mem, 0.9f, c * 0.1f);
        float sp = (mem > 0.5f) ? 1.0f : 0.0f;
        mem = fmaf(sp, -0.5f, mem);
        ro0 = fmaf(sp, wo0, ro0);
        ro1 = fmaf(sp, wo1, ro1);
      }
    } else if (tau + 1 < ntiles) {
      // ---- pipeline: encode next tile into the other E buffer ----
      int nxt = cur ^ 1;
      encode_tile(tid - 128, tau + 1, &Ebuf[nxt][0][0], &Ebuf[nxt][1][0], xrow4);
    }
    __syncthreads();               // B3: scan done (Hn reusable), E[next] ready
  }

  // ---- epilogue: readout reduction (enc waves hold zeros) ----
  float r0 = wave_red_sum(ro0);
  float r1 = wave_red_sum(ro1);
  if ((tid & 63) == 0) { red[w * 64] = r0; red[w * 64 + 1] = r1; }
  __syncthreads();
  if (tid == 0) {
    float R0 = (red[0] + red[64]) + (red[128] + red[192]);
    float R1 = (red[1] + red[65]) + (red[129] + red[193]);
    out[2 * b]     = R0 + (float)T * b_out[0];
    out[2 * b + 1] = R1 + (float)T * b_out[1];
  }
}

extern "C" void kernel_launch(void* const* d_in, const int* in_sizes, int n_in,
                              void* d_out, int out_size, void* d_ws, size_t ws_size,
                              hipStream_t stream) {
  const float* x    = (const float*)d_in[0];
  const float* Win  = (const float*)d_in[1];
  const float* bin  = (const float*)d_in[2];
  const float* lng  = (const float*)d_in[3];
  const float* lnb  = (const float*)d_in[4];
  const float* Wout = (const float*)d_in[5];
  const float* bout = (const float*)d_in[6];
  float* out = (float*)d_out;

  int B = out_size / 2;                 // 2048
  int T = in_sizes[0] / (B * 4);        // 512

  snn_mfma_kernel<<<dim3(B), dim3(256), 0, stream>>>(
      x, Win, bin, lng, lnb, Wout, bout, out, T);
}